// Round 3
// baseline (1863.046 us; speedup 1.0000x reference)
//
#include <hip/hip_runtime.h>
#include <cstdint>
#include <cstddef>

typedef unsigned short u16;
typedef __bf16 bf16x8 __attribute__((ext_vector_type(8)));
typedef float f32x4 __attribute__((ext_vector_type(4)));

typedef __attribute__((address_space(1))) const void global_cvoid;
typedef __attribute__((address_space(3))) void lds_void;

__device__ __forceinline__ void async16(void* lds, const void* g) {
  __builtin_amdgcn_global_load_lds((global_cvoid*)g, (lds_void*)lds, 16, 0, 0);
}

__device__ __forceinline__ u16 f2bf(float f) {  // RNE fp32 -> bf16 bits
  uint32_t u = __float_as_uint(f);
  return (u16)((u + 0x7fffu + ((u >> 16) & 1u)) >> 16);
}

// Pack 4 fp32 -> 12 u16 {h,l,h} stream, written as 6 dwords.
__device__ __forceinline__ void pack4_hlh(uint32_t* dst, const float* v) {
  u16 h[4], l[4];
#pragma unroll
  for (int u = 0; u < 4; ++u) {
    h[u] = f2bf(v[u]);
    float hf = __uint_as_float((uint32_t)h[u] << 16);
    l[u] = f2bf(v[u] - hf);
  }
  dst[0] = (uint32_t)h[0] | ((uint32_t)l[0] << 16);
  dst[1] = (uint32_t)h[0] | ((uint32_t)h[1] << 16);
  dst[2] = (uint32_t)l[1] | ((uint32_t)h[1] << 16);
  dst[3] = (uint32_t)h[2] | ((uint32_t)l[2] << 16);
  dst[4] = (uint32_t)h[2] | ((uint32_t)h[3] << 16);
  dst[5] = (uint32_t)l[3] | ((uint32_t)h[3] << 16);
}

// ---------------------------------------------------------------------------
// Pack W (A operand): out[d][3c+{0,1,2}] = {hi, hi, lo} of W[d][c]. K rows=1024.
// ---------------------------------------------------------------------------
__global__ __launch_bounds__(256) void pack_w(const float* __restrict__ W,
                                              u16* __restrict__ out) {
  int idx = blockIdx.x * 256 + threadIdx.x;
  int d = idx >> 10, c = idx & 1023;
  float f = W[idx];
  u16 h = f2bf(f);
  float hf = __uint_as_float((uint32_t)h << 16);
  u16 l = f2bf(f - hf);
  u16* dst = out + (size_t)d * 3072 + 3 * c;
  dst[0] = h; dst[1] = h; dst[2] = l;
}

// ---------------------------------------------------------------------------
// Pack+transpose X (B operand): out[b][n][3c+{0,1,2}] = {h,l,h} of X[b][c][n].
// ---------------------------------------------------------------------------
__global__ __launch_bounds__(256) void pack_x(const float* __restrict__ X,
                                              u16* __restrict__ out) {
  const int b = blockIdx.z, c0 = blockIdx.y * 32, n0 = blockIdx.x * 32;
  __shared__ float tile[32][33];
  const float* src = X + ((size_t)b * 1024 + c0) * 1024 + n0;
  const int tc = threadIdx.x >> 5, tn = threadIdx.x & 31;
#pragma unroll
  for (int i = 0; i < 4; ++i)
    tile[tc + i * 8][tn] = src[(size_t)(tc + i * 8) * 1024 + tn];
  __syncthreads();
  const int nl = threadIdx.x >> 3, cg = (threadIdx.x & 7) * 4;
  float v[4];
#pragma unroll
  for (int u = 0; u < 4; ++u) v[u] = tile[cg + u][nl];
  uint32_t* dst = (uint32_t*)(out + ((size_t)b * 1024 + n0 + nl) * 3072 +
                              (size_t)(c0 + cg) * 3);
  pack4_hlh(dst, v);
}

// ---------------------------------------------------------------------------
// Pack+transpose Tx: Tx[b][1024 c][77 t] -> TxPk[b][128 t][3072] {h,l,h},
// rows t>=77 zeroed. grid (4 t-tiles, 32 c-tiles, 16 b).
// ---------------------------------------------------------------------------
__global__ __launch_bounds__(256) void pack_tx(const float* __restrict__ Tx,
                                               u16* __restrict__ out) {
  const int b = blockIdx.z, c0 = blockIdx.y * 32, t0 = blockIdx.x * 32;
  __shared__ float tile[32][33];
  const float* src = Tx + ((size_t)b * 1024 + c0) * 77;
  const int tc = threadIdx.x >> 5, tn = threadIdx.x & 31;
#pragma unroll
  for (int i = 0; i < 4; ++i) {
    int t = t0 + tn;
    tile[tc + i * 8][tn] = (t < 77) ? src[(size_t)(tc + i * 8) * 77 + t] : 0.f;
  }
  __syncthreads();
  const int nl = threadIdx.x >> 3, cg = (threadIdx.x & 7) * 4;
  float v[4];
#pragma unroll
  for (int u = 0; u < 4; ++u) v[u] = tile[cg + u][nl];
  uint32_t* dst = (uint32_t*)(out + ((size_t)b * 128 + t0 + nl) * 3072 +
                              (size_t)(c0 + cg) * 3);
  pack4_hlh(dst, v);
}

// ---------------------------------------------------------------------------
// MFMA GEMM: Y[b][d][n] = sum_{k'} Apk[d][k'] * Bpk[b][n][k'] + bias[d]
// ---------------------------------------------------------------------------
__global__ __launch_bounds__(256) void gemm_mfma(
    const u16* __restrict__ Apk, const u16* __restrict__ Bpk,
    const float* __restrict__ bias, float* __restrict__ Y)
{
  const int b  = blockIdx.z;
  const int d0 = blockIdx.y * 128;
  const int n0 = blockIdx.x * 128;
  const int tid  = threadIdx.x;
  const int lane = tid & 63;
  const int w    = tid >> 6;
  const int wm   = w >> 1, wn = w & 1;

  __shared__ __align__(16) char smem[16384];
  char* smA = smem;
  char* smB = smem + 8192;

  const int lr = lane & 15;
  const int lk = (lane >> 4) * 8;

  const u16* Bb = Bpk + (size_t)b * 1024 * 3072;
  const char* gA0 = (const char*)(Apk + ((size_t)(d0 + (w * 2 + 0) * 16 + lr) * 3072 + lk));
  const char* gA1 = (const char*)(Apk + ((size_t)(d0 + (w * 2 + 1) * 16 + lr) * 3072 + lk));
  const char* gB0 = (const char*)(Bb  + ((size_t)(n0 + (w * 2 + 0) * 16 + lr) * 3072 + lk));
  const char* gB1 = (const char*)(Bb  + ((size_t)(n0 + (w * 2 + 1) * 16 + lr) * 3072 + lk));

  f32x4 acc[4][4];
#pragma unroll
  for (int i = 0; i < 4; ++i)
#pragma unroll
    for (int j = 0; j < 4; ++j) acc[i][j] = (f32x4){0.f, 0.f, 0.f, 0.f};

  for (int ks = 0; ks < 96; ++ks) {
    __syncthreads();
    async16(smA + (w * 2 + 0) * 1024, gA0);
    async16(smA + (w * 2 + 1) * 1024, gA1);
    async16(smB + (w * 2 + 0) * 1024, gB0);
    async16(smB + (w * 2 + 1) * 1024, gB1);
    gA0 += 64; gA1 += 64; gB0 += 64; gB1 += 64;
    __syncthreads();

    bf16x8 af[4], bfv[4];
#pragma unroll
    for (int i = 0; i < 4; ++i)
      af[i] = *(const bf16x8*)(smA + (wm * 4 + i) * 1024 + lane * 16);
#pragma unroll
    for (int j = 0; j < 4; ++j)
      bfv[j] = *(const bf16x8*)(smB + (wn * 4 + j) * 1024 + lane * 16);
#pragma unroll
    for (int i = 0; i < 4; ++i)
#pragma unroll
      for (int j = 0; j < 4; ++j)
        acc[i][j] = __builtin_amdgcn_mfma_f32_16x16x32_bf16(af[i], bfv[j], acc[i][j], 0, 0, 0);
  }

#pragma unroll
  for (int i = 0; i < 4; ++i) {
    const int dbase = d0 + wm * 64 + i * 16 + (lane >> 4) * 4;
    const float4 bv = *(const float4*)(bias + dbase);
#pragma unroll
    for (int j = 0; j < 4; ++j) {
      const int n = n0 + wn * 64 + j * 16 + lr;
      float* yp = Y + ((size_t)b * 1024 + dbase) * 1024 + n;
      yp[0]        = acc[i][j].x + bv.x;
      yp[1024]     = acc[i][j].y + bv.y;
      yp[2 * 1024] = acc[i][j].z + bv.z;
      yp[3 * 1024] = acc[i][j].w + bv.w;
    }
  }
}

// ---------------------------------------------------------------------------
// KV MFMA GEMM: kv[b][e][t(80pad)] = sum Wkv[e][c] Tx[b][c][t] + bkv[e]
// A = WkvPk [2048][3072], B = TxPk [b][128][3072], N=128 (80 valid), one n-tile.
// grid (16 e-tiles, 16 b).
// ---------------------------------------------------------------------------
__global__ __launch_bounds__(256) void gemm_kv_mfma(
    const u16* __restrict__ Apk, const u16* __restrict__ Bpk,
    const float* __restrict__ bias, float* __restrict__ Y)
{
  const int b  = blockIdx.y;
  const int d0 = blockIdx.x * 128;
  const int tid  = threadIdx.x;
  const int lane = tid & 63;
  const int w    = tid >> 6;
  const int wm   = w >> 1, wn = w & 1;

  __shared__ __align__(16) char smem[16384];
  char* smA = smem;
  char* smB = smem + 8192;

  const int lr = lane & 15;
  const int lk = (lane >> 4) * 8;

  const u16* Bb = Bpk + (size_t)b * 128 * 3072;
  const char* gA0 = (const char*)(Apk + ((size_t)(d0 + (w * 2 + 0) * 16 + lr) * 3072 + lk));
  const char* gA1 = (const char*)(Apk + ((size_t)(d0 + (w * 2 + 1) * 16 + lr) * 3072 + lk));
  const char* gB0 = (const char*)(Bb  + ((size_t)((w * 2 + 0) * 16 + lr) * 3072 + lk));
  const char* gB1 = (const char*)(Bb  + ((size_t)((w * 2 + 1) * 16 + lr) * 3072 + lk));

  f32x4 acc[4][4];
#pragma unroll
  for (int i = 0; i < 4; ++i)
#pragma unroll
    for (int j = 0; j < 4; ++j) acc[i][j] = (f32x4){0.f, 0.f, 0.f, 0.f};

  for (int ks = 0; ks < 96; ++ks) {
    __syncthreads();
    async16(smA + (w * 2 + 0) * 1024, gA0);
    async16(smA + (w * 2 + 1) * 1024, gA1);
    async16(smB + (w * 2 + 0) * 1024, gB0);
    async16(smB + (w * 2 + 1) * 1024, gB1);
    gA0 += 64; gA1 += 64; gB0 += 64; gB1 += 64;
    __syncthreads();

    bf16x8 af[4], bfv[4];
#pragma unroll
    for (int i = 0; i < 4; ++i)
      af[i] = *(const bf16x8*)(smA + (wm * 4 + i) * 1024 + lane * 16);
#pragma unroll
    for (int j = 0; j < 4; ++j)
      bfv[j] = *(const bf16x8*)(smB + (wn * 4 + j) * 1024 + lane * 16);
#pragma unroll
    for (int i = 0; i < 4; ++i)
#pragma unroll
      for (int j = 0; j < 4; ++j)
        acc[i][j] = __builtin_amdgcn_mfma_f32_16x16x32_bf16(af[i], bfv[j], acc[i][j], 0, 0, 0);
  }

#pragma unroll
  for (int i = 0; i < 4; ++i) {
    const int dbase = d0 + wm * 64 + i * 16 + (lane >> 4) * 4;
    const float4 bv = *(const float4*)(bias + dbase);
#pragma unroll
    for (int j = 0; j < 4; ++j) {
      const int n = wn * 64 + j * 16 + lr;
      if (n < 80) {
        float* yp = Y + ((size_t)b * 2048 + dbase) * 80 + n;
        yp[0]      = acc[i][j].x + bv.x;
        yp[80]     = acc[i][j].y + bv.y;
        yp[160]    = acc[i][j].z + bv.z;
        yp[240]    = acc[i][j].w + bv.w;
      }
    }
  }
}

// ---------------------------------------------------------------------------
// Fused attention + B-operand pack. kv layout [b][2048][80] (cols 77..79 =
// bias garbage in K region -> excluded from softmax; V pad multiplied by 0).
// 128 threads, 2 n each; grid (4 n-chunks of 256, 8 h, 16 b) = 512 blocks.
// Output: Xpk[b][n][3c] {h,l,h}, c = h*128 + d.
// ---------------------------------------------------------------------------
__global__ __launch_bounds__(128, 2) void attn_fused(
    const float* __restrict__ q,   // [B][1024][1024]
    const float* __restrict__ kv,  // [B][2048][80]
    u16* __restrict__ Xpk)         // [B][1024][3072]
{
  const int b   = blockIdx.z;
  const int h   = blockIdx.y;
  const int n0  = blockIdx.x * 256;
  const int tid = threadIdx.x;
  const float scale = 0.08838834764831845f;  // 128^-0.5

  __shared__ float sk[128 * 80];
  float4* sk4 = (float4*)sk;

  const float4* kvb4 = (const float4*)(kv + ((size_t)b * 2048 + h * 256) * 80);

  // stage K (128 rows x 80 = 2560 float4s)
#pragma unroll
  for (int i = 0; i < 20; ++i) sk4[tid + i * 128] = kvb4[tid + i * 128];
  __syncthreads();

  float s0[80], s1[80];
#pragma unroll
  for (int t = 0; t < 80; ++t) { s0[t] = 0.f; s1[t] = 0.f; }

  const float* qp = q + ((size_t)b * 1024 + h * 128) * 1024 + n0 + tid;
#pragma unroll 4
  for (int d = 0; d < 128; ++d) {
    float qa = qp[(size_t)d * 1024];
    float qb = qp[(size_t)d * 1024 + 128];
#pragma unroll
    for (int tc = 0; tc < 20; ++tc) {
      float4 k4 = sk4[d * 20 + tc];
      s0[tc * 4 + 0] += qa * k4.x; s1[tc * 4 + 0] += qb * k4.x;
      s0[tc * 4 + 1] += qa * k4.y; s1[tc * 4 + 1] += qb * k4.y;
      s0[tc * 4 + 2] += qa * k4.z; s1[tc * 4 + 2] += qb * k4.z;
      s0[tc * 4 + 3] += qa * k4.w; s1[tc * 4 + 3] += qb * k4.w;
    }
  }

  float m0 = -3.0e38f, m1 = -3.0e38f;
#pragma unroll
  for (int t = 0; t < 77; ++t) { m0 = fmaxf(m0, s0[t]); m1 = fmaxf(m1, s1[t]); }
  float sum0 = 0.f, sum1 = 0.f;
#pragma unroll
  for (int t = 0; t < 77; ++t) {
    s0[t] = __expf((s0[t] - m0) * scale); sum0 += s0[t];
    s1[t] = __expf((s1[t] - m1) * scale); sum1 += s1[t];
  }
  const float i0 = 1.f / sum0, i1 = 1.f / sum1;
#pragma unroll
  for (int t = 0; t < 77; ++t) { s0[t] *= i0; s1[t] *= i1; }
  s0[77] = s0[78] = s0[79] = 0.f;
  s1[77] = s1[78] = s1[79] = 0.f;

  __syncthreads();
  // stage V
  const float4* vvb4 = kvb4 + 2560;
#pragma unroll
  for (int i = 0; i < 20; ++i) sk4[tid + i * 128] = vvb4[tid + i * 128];
  __syncthreads();

  const int n = n0 + tid;
  uint32_t* xp0 = (uint32_t*)Xpk + (size_t)(b * 1024 + n) * 1536 + h * 192;
  uint32_t* xp1 = xp0 + (size_t)128 * 1536;

#pragma unroll
  for (int dblk = 0; dblk < 16; ++dblk) {
    float a0[8], a1[8];
#pragma unroll
    for (int dd = 0; dd < 8; ++dd) { a0[dd] = 0.f; a1[dd] = 0.f; }
#pragma unroll
    for (int dd = 0; dd < 8; ++dd) {
      const int d = dblk * 8 + dd;
#pragma unroll
      for (int tc = 0; tc < 20; ++tc) {
        float4 v4 = sk4[d * 20 + tc];
        a0[dd] += v4.x * s0[tc * 4 + 0] + v4.y * s0[tc * 4 + 1] +
                  v4.z * s0[tc * 4 + 2] + v4.w * s0[tc * 4 + 3];
        a1[dd] += v4.x * s1[tc * 4 + 0] + v4.y * s1[tc * 4 + 1] +
                  v4.z * s1[tc * 4 + 2] + v4.w * s1[tc * 4 + 3];
      }
    }
    pack4_hlh(xp0 + dblk * 12,     a0);
    pack4_hlh(xp0 + dblk * 12 + 6, a0 + 4);
    pack4_hlh(xp1 + dblk * 12,     a1);
    pack4_hlh(xp1 + dblk * 12 + 6, a1 + 4);
  }
}

// ---------------------------------------------------------------------------
extern "C" void kernel_launch(void* const* d_in, const int* in_sizes, int n_in,
                              void* d_out, int out_size, void* d_ws, size_t ws_size,
                              hipStream_t stream) {
  const float* Vx  = (const float*)d_in[0];
  const float* Tx  = (const float*)d_in[1];
  const float* Wq  = (const float*)d_in[2];
  const float* bq  = (const float*)d_in[3];
  const float* Wkv = (const float*)d_in[4];
  const float* bkv = (const float*)d_in[5];
  const float* Wp  = (const float*)d_in[6];
  const float* bp  = (const float*)d_in[7];
  float* out = (float*)d_out;

  char* ws = (char*)d_ws;
  const size_t MiB = (size_t)1 << 20;
  float* q      = (float*)(ws + 0);           // 64 MiB
  u16*   Xpk    = (u16*)(ws + 64 * MiB);      // 96 MiB (Vx-pack, then attn-out pack)
  float* kvbuf  = (float*)(ws + 160 * MiB);   // 16*2048*80*4 = 10.5 MiB
  u16*   WqPk   = (u16*)(ws + 171 * MiB);     // 6 MiB
  u16*   WpPk   = (u16*)(ws + 177 * MiB);     // 6 MiB
  u16*   WkvPk  = (u16*)(ws + 183 * MiB);     // 12 MiB
  u16*   TxPk   = (u16*)(ws + 195 * MiB);     // 16*128*3072*2 = 12 MiB

  pack_w<<<4096, 256, 0, stream>>>(Wq, WqPk);
  pack_w<<<4096, 256, 0, stream>>>(Wp, WpPk);
  pack_w<<<8192, 256, 0, stream>>>(Wkv, WkvPk);
  pack_x<<<dim3(32, 32, 16), 256, 0, stream>>>(Vx, Xpk);
  pack_tx<<<dim3(4, 32, 16), 256, 0, stream>>>(Tx, TxPk);
  gemm_mfma<<<dim3(8, 8, 16), 256, 0, stream>>>(WqPk, Xpk, bq, q);
  gemm_kv_mfma<<<dim3(16, 16), 256, 0, stream>>>(WkvPk, TxPk, bkv, kvbuf);
  attn_fused<<<dim3(4, 8, 16), 128, 0, stream>>>(q, kvbuf, Xpk);
  gemm_mfma<<<dim3(8, 8, 16), 256, 0, stream>>>(WpPk, Xpk, bp, out);
}

// Round 4
// 990.139 us; speedup vs baseline: 1.8816x; 1.8816x over previous
//
#include <hip/hip_runtime.h>
#include <cstdint>
#include <cstddef>

typedef unsigned short u16;
typedef __bf16 bf16x8 __attribute__((ext_vector_type(8)));
typedef float f32x4 __attribute__((ext_vector_type(4)));

typedef __attribute__((address_space(1))) const void global_cvoid;
typedef __attribute__((address_space(3))) void lds_void;

__device__ __forceinline__ void async16(void* lds, const void* g) {
  __builtin_amdgcn_global_load_lds((global_cvoid*)g, (lds_void*)lds, 16, 0, 0);
}

__device__ __forceinline__ u16 f2bf(float f) {  // RNE fp32 -> bf16 bits
  uint32_t u = __float_as_uint(f);
  return (u16)((u + 0x7fffu + ((u >> 16) & 1u)) >> 16);
}

// Pack 4 fp32 -> 12 u16 {h,l,h} stream, written as 6 dwords.
__device__ __forceinline__ void pack4_hlh(uint32_t* dst, const float* v) {
  u16 h[4], l[4];
#pragma unroll
  for (int u = 0; u < 4; ++u) {
    h[u] = f2bf(v[u]);
    float hf = __uint_as_float((uint32_t)h[u] << 16);
    l[u] = f2bf(v[u] - hf);
  }
  dst[0] = (uint32_t)h[0] | ((uint32_t)l[0] << 16);
  dst[1] = (uint32_t)h[0] | ((uint32_t)h[1] << 16);
  dst[2] = (uint32_t)l[1] | ((uint32_t)h[1] << 16);
  dst[3] = (uint32_t)h[2] | ((uint32_t)l[2] << 16);
  dst[4] = (uint32_t)h[2] | ((uint32_t)h[3] << 16);
  dst[5] = (uint32_t)l[3] | ((uint32_t)h[3] << 16);
}

// ---------------------------------------------------------------------------
// Pack W (A operand): out[d][3c+{0,1,2}] = {hi, hi, lo} of W[d][c].
// ---------------------------------------------------------------------------
__global__ __launch_bounds__(256) void pack_w(const float* __restrict__ W,
                                              u16* __restrict__ out) {
  int idx = blockIdx.x * 256 + threadIdx.x;
  int d = idx >> 10, c = idx & 1023;
  float f = W[idx];
  u16 h = f2bf(f);
  float hf = __uint_as_float((uint32_t)h << 16);
  u16 l = f2bf(f - hf);
  u16* dst = out + (size_t)d * 3072 + 3 * c;
  dst[0] = h; dst[1] = h; dst[2] = l;
}

// ---------------------------------------------------------------------------
// Pack+transpose X (B operand): out[b][n][3c+{0,1,2}] = {h,l,h} of X[b][c][n].
// ---------------------------------------------------------------------------
__global__ __launch_bounds__(256) void pack_x(const float* __restrict__ X,
                                              u16* __restrict__ out) {
  const int b = blockIdx.z, c0 = blockIdx.y * 32, n0 = blockIdx.x * 32;
  __shared__ float tile[32][33];
  const float* src = X + ((size_t)b * 1024 + c0) * 1024 + n0;
  const int tc = threadIdx.x >> 5, tn = threadIdx.x & 31;
#pragma unroll
  for (int i = 0; i < 4; ++i)
    tile[tc + i * 8][tn] = src[(size_t)(tc + i * 8) * 1024 + tn];
  __syncthreads();
  const int nl = threadIdx.x >> 3, cg = (threadIdx.x & 7) * 4;
  float v[4];
#pragma unroll
  for (int u = 0; u < 4; ++u) v[u] = tile[cg + u][nl];
  uint32_t* dst = (uint32_t*)(out + ((size_t)b * 1024 + n0 + nl) * 3072 +
                              (size_t)(c0 + cg) * 3);
  pack4_hlh(dst, v);
}

// ---------------------------------------------------------------------------
// Pack+transpose Tx: Tx[b][1024 c][77 t] -> TxPk[b][128 t][3072] {h,l,h},
// rows t>=77 zeroed. grid (4 t-tiles, 32 c-tiles, 16 b).
// ---------------------------------------------------------------------------
__global__ __launch_bounds__(256) void pack_tx(const float* __restrict__ Tx,
                                               u16* __restrict__ out) {
  const int b = blockIdx.z, c0 = blockIdx.y * 32, t0 = blockIdx.x * 32;
  __shared__ float tile[32][33];
  const float* src = Tx + ((size_t)b * 1024 + c0) * 77;
  const int tc = threadIdx.x >> 5, tn = threadIdx.x & 31;
#pragma unroll
  for (int i = 0; i < 4; ++i) {
    int t = t0 + tn;
    tile[tc + i * 8][tn] = (t < 77) ? src[(size_t)(tc + i * 8) * 77 + t] : 0.f;
  }
  __syncthreads();
  const int nl = threadIdx.x >> 3, cg = (threadIdx.x & 7) * 4;
  float v[4];
#pragma unroll
  for (int u = 0; u < 4; ++u) v[u] = tile[cg + u][nl];
  uint32_t* dst = (uint32_t*)(out + ((size_t)b * 128 + t0 + nl) * 3072 +
                              (size_t)(c0 + cg) * 3);
  pack4_hlh(dst, v);
}

// ---------------------------------------------------------------------------
// MFMA GEMM: Y[b][d][n] = sum_{k'} Apk[d][k'] * Bpk[b][n][k'] + bias[d]
// ---------------------------------------------------------------------------
__global__ __launch_bounds__(256) void gemm_mfma(
    const u16* __restrict__ Apk, const u16* __restrict__ Bpk,
    const float* __restrict__ bias, float* __restrict__ Y)
{
  const int b  = blockIdx.z;
  const int d0 = blockIdx.y * 128;
  const int n0 = blockIdx.x * 128;
  const int tid  = threadIdx.x;
  const int lane = tid & 63;
  const int w    = tid >> 6;
  const int wm   = w >> 1, wn = w & 1;

  __shared__ __align__(16) char smem[16384];
  char* smA = smem;
  char* smB = smem + 8192;

  const int lr = lane & 15;
  const int lk = (lane >> 4) * 8;

  const u16* Bb = Bpk + (size_t)b * 1024 * 3072;
  const char* gA0 = (const char*)(Apk + ((size_t)(d0 + (w * 2 + 0) * 16 + lr) * 3072 + lk));
  const char* gA1 = (const char*)(Apk + ((size_t)(d0 + (w * 2 + 1) * 16 + lr) * 3072 + lk));
  const char* gB0 = (const char*)(Bb  + ((size_t)(n0 + (w * 2 + 0) * 16 + lr) * 3072 + lk));
  const char* gB1 = (const char*)(Bb  + ((size_t)(n0 + (w * 2 + 1) * 16 + lr) * 3072 + lk));

  f32x4 acc[4][4];
#pragma unroll
  for (int i = 0; i < 4; ++i)
#pragma unroll
    for (int j = 0; j < 4; ++j) acc[i][j] = (f32x4){0.f, 0.f, 0.f, 0.f};

  for (int ks = 0; ks < 96; ++ks) {
    __syncthreads();
    async16(smA + (w * 2 + 0) * 1024, gA0);
    async16(smA + (w * 2 + 1) * 1024, gA1);
    async16(smB + (w * 2 + 0) * 1024, gB0);
    async16(smB + (w * 2 + 1) * 1024, gB1);
    gA0 += 64; gA1 += 64; gB0 += 64; gB1 += 64;
    __syncthreads();

    bf16x8 af[4], bfv[4];
#pragma unroll
    for (int i = 0; i < 4; ++i)
      af[i] = *(const bf16x8*)(smA + (wm * 4 + i) * 1024 + lane * 16);
#pragma unroll
    for (int j = 0; j < 4; ++j)
      bfv[j] = *(const bf16x8*)(smB + (wn * 4 + j) * 1024 + lane * 16);
#pragma unroll
    for (int i = 0; i < 4; ++i)
#pragma unroll
      for (int j = 0; j < 4; ++j)
        acc[i][j] = __builtin_amdgcn_mfma_f32_16x16x32_bf16(af[i], bfv[j], acc[i][j], 0, 0, 0);
  }

#pragma unroll
  for (int i = 0; i < 4; ++i) {
    const int dbase = d0 + wm * 64 + i * 16 + (lane >> 4) * 4;
    const float4 bv = *(const float4*)(bias + dbase);
#pragma unroll
    for (int j = 0; j < 4; ++j) {
      const int n = n0 + wn * 64 + j * 16 + lr;
      float* yp = Y + ((size_t)b * 1024 + dbase) * 1024 + n;
      yp[0]        = acc[i][j].x + bv.x;
      yp[1024]     = acc[i][j].y + bv.y;
      yp[2 * 1024] = acc[i][j].z + bv.z;
      yp[3 * 1024] = acc[i][j].w + bv.w;
    }
  }
}

// ---------------------------------------------------------------------------
// KV MFMA GEMM: kv[b][e][t(80pad)] = sum Wkv[e][c] Tx[b][c][t] + bkv[e]
// ---------------------------------------------------------------------------
__global__ __launch_bounds__(256) void gemm_kv_mfma(
    const u16* __restrict__ Apk, const u16* __restrict__ Bpk,
    const float* __restrict__ bias, float* __restrict__ Y)
{
  const int b  = blockIdx.y;
  const int d0 = blockIdx.x * 128;
  const int tid  = threadIdx.x;
  const int lane = tid & 63;
  const int w    = tid >> 6;
  const int wm   = w >> 1, wn = w & 1;

  __shared__ __align__(16) char smem[16384];
  char* smA = smem;
  char* smB = smem + 8192;

  const int lr = lane & 15;
  const int lk = (lane >> 4) * 8;

  const u16* Bb = Bpk + (size_t)b * 128 * 3072;
  const char* gA0 = (const char*)(Apk + ((size_t)(d0 + (w * 2 + 0) * 16 + lr) * 3072 + lk));
  const char* gA1 = (const char*)(Apk + ((size_t)(d0 + (w * 2 + 1) * 16 + lr) * 3072 + lk));
  const char* gB0 = (const char*)(Bb  + ((size_t)((w * 2 + 0) * 16 + lr) * 3072 + lk));
  const char* gB1 = (const char*)(Bb  + ((size_t)((w * 2 + 1) * 16 + lr) * 3072 + lk));

  f32x4 acc[4][4];
#pragma unroll
  for (int i = 0; i < 4; ++i)
#pragma unroll
    for (int j = 0; j < 4; ++j) acc[i][j] = (f32x4){0.f, 0.f, 0.f, 0.f};

  for (int ks = 0; ks < 96; ++ks) {
    __syncthreads();
    async16(smA + (w * 2 + 0) * 1024, gA0);
    async16(smA + (w * 2 + 1) * 1024, gA1);
    async16(smB + (w * 2 + 0) * 1024, gB0);
    async16(smB + (w * 2 + 1) * 1024, gB1);
    gA0 += 64; gA1 += 64; gB0 += 64; gB1 += 64;
    __syncthreads();

    bf16x8 af[4], bfv[4];
#pragma unroll
    for (int i = 0; i < 4; ++i)
      af[i] = *(const bf16x8*)(smA + (wm * 4 + i) * 1024 + lane * 16);
#pragma unroll
    for (int j = 0; j < 4; ++j)
      bfv[j] = *(const bf16x8*)(smB + (wn * 4 + j) * 1024 + lane * 16);
#pragma unroll
    for (int i = 0; i < 4; ++i)
#pragma unroll
      for (int j = 0; j < 4; ++j)
        acc[i][j] = __builtin_amdgcn_mfma_f32_16x16x32_bf16(af[i], bfv[j], acc[i][j], 0, 0, 0);
  }

#pragma unroll
  for (int i = 0; i < 4; ++i) {
    const int dbase = d0 + wm * 64 + i * 16 + (lane >> 4) * 4;
    const float4 bv = *(const float4*)(bias + dbase);
#pragma unroll
    for (int j = 0; j < 4; ++j) {
      const int n = wn * 64 + j * 16 + lr;
      if (n < 80) {
        float* yp = Y + ((size_t)b * 2048 + dbase) * 80 + n;
        yp[0]      = acc[i][j].x + bv.x;
        yp[80]     = acc[i][j].y + bv.y;
        yp[160]    = acc[i][j].z + bv.z;
        yp[240]    = acc[i][j].w + bv.w;
      }
    }
  }
}

// ---------------------------------------------------------------------------
// Attention (round-2 proven form): 2 n/thread, scores in registers (no spill
// under __launch_bounds__(256,1) -> VGPR budget 512). kv layout [b][2048][80];
// K pad cols (77..79) excluded from softmax, V pad multiplied by p=0.
// Coalesced fp32 output [b][c][n]. grid (2, 8, 16), 256 threads.
// ---------------------------------------------------------------------------
__global__ __launch_bounds__(256, 1) void attn_kernel2(
    const float* __restrict__ q,   // [B][1024][1024]
    const float* __restrict__ kv,  // [B][2048][80]
    float* __restrict__ o)         // [B][1024][1024]
{
  const int b   = blockIdx.z;
  const int h   = blockIdx.y;
  const int n0  = blockIdx.x * 512;
  const int tid = threadIdx.x;
  const float scale = 0.08838834764831845f;  // 128^-0.5

  __shared__ float sk[128 * 80];
  float4* sk4 = (float4*)sk;

  const float4* kvb4 = (const float4*)(kv + ((size_t)b * 2048 + h * 256) * 80);

  // stage K: 128 rows x 20 float4 = 2560 float4s
#pragma unroll
  for (int i = 0; i < 10; ++i) sk4[tid + i * 256] = kvb4[tid + i * 256];
  __syncthreads();

  float s0[80], s1[80];
#pragma unroll
  for (int t = 0; t < 80; ++t) { s0[t] = 0.f; s1[t] = 0.f; }

  const float* qp = q + ((size_t)b * 1024 + h * 128) * 1024 + n0 + tid;
#pragma unroll 4
  for (int d = 0; d < 128; ++d) {
    float qa = qp[(size_t)d * 1024];
    float qb = qp[(size_t)d * 1024 + 256];
#pragma unroll
    for (int tc = 0; tc < 20; ++tc) {
      float4 k4 = sk4[d * 20 + tc];
      s0[tc * 4 + 0] += qa * k4.x; s1[tc * 4 + 0] += qb * k4.x;
      s0[tc * 4 + 1] += qa * k4.y; s1[tc * 4 + 1] += qb * k4.y;
      s0[tc * 4 + 2] += qa * k4.z; s1[tc * 4 + 2] += qb * k4.z;
      s0[tc * 4 + 3] += qa * k4.w; s1[tc * 4 + 3] += qb * k4.w;
    }
  }

  float m0 = -3.0e38f, m1 = -3.0e38f;
#pragma unroll
  for (int t = 0; t < 77; ++t) { m0 = fmaxf(m0, s0[t]); m1 = fmaxf(m1, s1[t]); }
  float sum0 = 0.f, sum1 = 0.f;
#pragma unroll
  for (int t = 0; t < 77; ++t) {
    s0[t] = __expf((s0[t] - m0) * scale); sum0 += s0[t];
    s1[t] = __expf((s1[t] - m1) * scale); sum1 += s1[t];
  }
  const float i0 = 1.f / sum0, i1 = 1.f / sum1;
#pragma unroll
  for (int t = 0; t < 77; ++t) { s0[t] *= i0; s1[t] *= i1; }
  s0[77] = s0[78] = s0[79] = 0.f;
  s1[77] = s1[78] = s1[79] = 0.f;

  __syncthreads();
  // stage V
  const float4* vvb4 = kvb4 + 2560;
#pragma unroll
  for (int i = 0; i < 10; ++i) sk4[tid + i * 256] = vvb4[tid + i * 256];
  __syncthreads();

  float* op = o + ((size_t)b * 1024 + h * 128) * 1024 + n0 + tid;
#pragma unroll
  for (int dblk = 0; dblk < 16; ++dblk) {
    float a0[8], a1[8];
#pragma unroll
    for (int dd = 0; dd < 8; ++dd) { a0[dd] = 0.f; a1[dd] = 0.f; }
#pragma unroll
    for (int dd = 0; dd < 8; ++dd) {
      const int d = dblk * 8 + dd;
#pragma unroll
      for (int tc = 0; tc < 20; ++tc) {
        float4 v4 = sk4[d * 20 + tc];
        a0[dd] += v4.x * s0[tc * 4 + 0] + v4.y * s0[tc * 4 + 1] +
                  v4.z * s0[tc * 4 + 2] + v4.w * s0[tc * 4 + 3];
        a1[dd] += v4.x * s1[tc * 4 + 0] + v4.y * s1[tc * 4 + 1] +
                  v4.z * s1[tc * 4 + 2] + v4.w * s1[tc * 4 + 3];
      }
    }
#pragma unroll
    for (int dd = 0; dd < 8; ++dd) {
      op[(size_t)(dblk * 8 + dd) * 1024]       = a0[dd];
      op[(size_t)(dblk * 8 + dd) * 1024 + 256] = a1[dd];
    }
  }
}

// ---------------------------------------------------------------------------
extern "C" void kernel_launch(void* const* d_in, const int* in_sizes, int n_in,
                              void* d_out, int out_size, void* d_ws, size_t ws_size,
                              hipStream_t stream) {
  const float* Vx  = (const float*)d_in[0];
  const float* Tx  = (const float*)d_in[1];
  const float* Wq  = (const float*)d_in[2];
  const float* bq  = (const float*)d_in[3];
  const float* Wkv = (const float*)d_in[4];
  const float* bkv = (const float*)d_in[5];
  const float* Wp  = (const float*)d_in[6];
  const float* bp  = (const float*)d_in[7];
  float* out = (float*)d_out;

  char* ws = (char*)d_ws;
  const size_t MiB = (size_t)1 << 20;
  // Lifetime-aliased layout (total 241 MiB):
  //   q        [0,   64)  MiB  — live gemm#1 .. attn
  //   attn_out [64, 128)  MiB  — written by attn; before that, the region
  //     holds WqPk(64-70), WkvPk(70-82), TxPk(82-94), all dead before attn.
  //   Xpk      [128, 224) MiB  — Vx-pack (dead after gemm#1), then attn-out pack
  //   kvbuf    [224, 235) MiB  — live kv_mfma .. attn
  //   WpPk     [235, 241) MiB  — live until final gemm
  float* q        = (float*)(ws + 0);
  float* attn_out = (float*)(ws + 64 * MiB);
  u16*   WqPk     = (u16*)(ws + 64 * MiB);
  u16*   WkvPk    = (u16*)(ws + 70 * MiB);
  u16*   TxPk     = (u16*)(ws + 82 * MiB);
  u16*   Xpk      = (u16*)(ws + 128 * MiB);
  float* kvbuf    = (float*)(ws + 224 * MiB);
  u16*   WpPk     = (u16*)(ws + 235 * MiB);

  pack_w<<<4096, 256, 0, stream>>>(Wq, WqPk);
  pack_w<<<4096, 256, 0, stream>>>(Wp, WpPk);
  pack_w<<<8192, 256, 0, stream>>>(Wkv, WkvPk);
  pack_x<<<dim3(32, 32, 16), 256, 0, stream>>>(Vx, Xpk);
  pack_tx<<<dim3(4, 32, 16), 256, 0, stream>>>(Tx, TxPk);
  gemm_mfma<<<dim3(8, 8, 16), 256, 0, stream>>>(WqPk, Xpk, bq, q);
  gemm_kv_mfma<<<dim3(16, 16), 256, 0, stream>>>(WkvPk, TxPk, bkv, kvbuf);
  attn_kernel2<<<dim3(2, 8, 16), 256, 0, stream>>>(q, kvbuf, attn_out);
  pack_x<<<dim3(32, 32, 16), 256, 0, stream>>>(attn_out, Xpk);
  gemm_mfma<<<dim3(8, 8, 16), 256, 0, stream>>>(WpPk, Xpk, bp, out);
}